// Round 4
// baseline (5263.068 us; speedup 1.0000x reference)
//
#include <hip/hip_runtime.h>
#include <math.h>

// ---- problem constants ----
#define BB 32
#define TT 720
#define CC 862
#define MM 4
#define LTOK 866          // C + M tokens
#define DD 512
#define HH 8
#define EE 64
#define FFD 2048
#define NTOK (BB * LTOK)  // 27712 = 433*64
#define NBH (BB * HH)     // 256
#define KPAD 736          // 720 padded to mult of 32 (embedding K)
#define NPADP 768         // 720 padded to mult of 128 (proj N tiles)

typedef unsigned short ushort_t;
typedef short s8v __attribute__((ext_vector_type(8)));
typedef float f4v __attribute__((ext_vector_type(4)));

__device__ __forceinline__ float wave_sum(float v) {
    #pragma unroll
    for (int off = 32; off; off >>= 1) v += __shfl_xor(v, off, 64);
    return v;
}
__device__ __forceinline__ float b2f(ushort_t u) {
    return __uint_as_float(((unsigned int)u) << 16);
}
__device__ __forceinline__ ushort_t f2b(float f) {
    unsigned int u = __float_as_uint(f);
    u = (u + 0x7FFFu + ((u >> 16) & 1u)) >> 16;
    return (ushort_t)u;
}

// ============ RevIN stats: mean/stdev per (b,c) over T ============
__global__ __launch_bounds__(256) void revin_stats(const float* __restrict__ x_enc,
                                                   float* __restrict__ mean,
                                                   float* __restrict__ stdev) {
    int b = blockIdx.y;
    int c = blockIdx.x * 64 + (threadIdx.x & 63);
    int g = threadIdx.x >> 6;
    float s = 0.f, s2 = 0.f;
    if (c < CC) {
        for (int t = g; t < TT; t += 4) {
            float v = x_enc[((size_t)b * TT + t) * CC + c];
            s += v; s2 += v * v;
        }
    }
    __shared__ float ls[4][64], ls2[4][64];
    ls[g][threadIdx.x & 63] = s; ls2[g][threadIdx.x & 63] = s2;
    __syncthreads();
    if (g == 0 && c < CC) {
        int cx = threadIdx.x & 63;
        s = ls[0][cx] + ls[1][cx] + ls[2][cx] + ls[3][cx];
        s2 = ls2[0][cx] + ls2[1][cx] + ls2[2][cx] + ls2[3][cx];
        float mu = s / (float)TT;
        float var = s2 / (float)TT - mu * mu;
        mean[b * CC + c] = mu;
        stdev[b * CC + c] = sqrtf(var + 1e-5f);
    }
}

// ============ build tokb[B,866,736] bf16: normalized channels + marks, K-padded ============
__global__ __launch_bounds__(256) void build_tok(const float* __restrict__ x_enc,
                                                 const float* __restrict__ x_mark,
                                                 const float* __restrict__ mean,
                                                 const float* __restrict__ stdev,
                                                 const float* __restrict__ rw,
                                                 const float* __restrict__ rb,
                                                 ushort_t* __restrict__ tok) {
    int b = blockIdx.z;
    int r0 = blockIdx.x * 32, t0 = blockIdx.y * 32;
    __shared__ float tile[32][33];
    int tx = threadIdx.x & 31, ty = threadIdx.x >> 5;
    #pragma unroll
    for (int kk = 0; kk < 4; kk++) {
        int t = t0 + ty + kk * 8, r = r0 + tx;
        float v = 0.f;
        if (t < TT && r < LTOK) {
            if (r < CC) {
                float xv = x_enc[((size_t)b * TT + t) * CC + r];
                v = (xv - mean[b * CC + r]) / stdev[b * CC + r] * rw[r] + rb[r];
            } else {
                v = x_mark[((size_t)b * TT + t) * MM + (r - CC)];
            }
        }
        tile[ty + kk * 8][tx] = v;
    }
    __syncthreads();
    #pragma unroll
    for (int kk = 0; kk < 4; kk++) {
        int r = r0 + ty + kk * 8, t = t0 + tx;
        if (r < LTOK && t < KPAD)
            tok[((size_t)b * LTOK + r) * KPAD + t] = f2b(tile[tx][ty + kk * 8]);
    }
}

// ============ weight convert+transpose: W[K,N] f32 -> Wt[NP,KP] bf16 (zero-padded) ============
__global__ __launch_bounds__(256) void convT(const float* __restrict__ W,
                                             ushort_t* __restrict__ Wt,
                                             int K, int N, int KP, int NP) {
    __shared__ float tile[32][33];
    int k0 = blockIdx.x * 32, n0 = blockIdx.y * 32;
    int tx = threadIdx.x & 31, ty = threadIdx.x >> 5;
    #pragma unroll
    for (int r = 0; r < 4; r++) {
        int k = k0 + ty + r * 8, n = n0 + tx;
        tile[ty + r * 8][tx] = (k < K && n < N) ? W[(size_t)k * N + n] : 0.f;
    }
    __syncthreads();
    #pragma unroll
    for (int r = 0; r < 4; r++) {
        int n = n0 + ty + r * 8, k = k0 + tx;
        if (n < NP && k < KP)
            Wt[(size_t)n * KP + k] = f2b(tile[tx][ty + r * 8]);
    }
}

// ============ bf16 MFMA GEMM: C = act(A[M,K] @ Bt[N,K]^T + bias) ============
#define GLL(g, l) __builtin_amdgcn_global_load_lds( \
    (const __attribute__((address_space(1))) void*)(g), \
    (__attribute__((address_space(3))) void*)(l), 16, 0, 0)

template <int ACT, bool OF, bool OB>
__global__ __launch_bounds__(256) void bgemm(const ushort_t* __restrict__ A,
                                             const ushort_t* __restrict__ Bt,
                                             const float* __restrict__ bias,
                                             float* __restrict__ Cf,
                                             ushort_t* __restrict__ Cb,
                                             int Mdim, int Kdim, int Nout) {
    __shared__ ushort_t As[128 * 32];
    __shared__ ushort_t Bs[128 * 32];
    const int tid = threadIdx.x;
    const int lane = tid & 63;
    const int wid = tid >> 6;
    const int m0 = blockIdx.y * 128;
    const int n0 = blockIdx.x * 128;
    const int wm = wid & 1, wn = wid >> 1;

    f4v acc[4][4];
    #pragma unroll
    for (int i = 0; i < 4; i++)
        #pragma unroll
        for (int j = 0; j < 4; j++)
            acc[i][j] = (f4v){0.f, 0.f, 0.f, 0.f};

    const int srow = wid * 16 + (lane >> 2);
    const int skq = (lane & 3) * 8;
    int ar0 = m0 + srow;       if (ar0 > Mdim - 1) ar0 = Mdim - 1;
    int ar1 = m0 + 64 + srow;  if (ar1 > Mdim - 1) ar1 = Mdim - 1;
    const ushort_t* gA0 = A + (size_t)ar0 * Kdim + skq;
    const ushort_t* gA1 = A + (size_t)ar1 * Kdim + skq;
    const ushort_t* gB0 = Bt + (size_t)(n0 + srow) * Kdim + skq;
    const ushort_t* gB1 = Bt + (size_t)(n0 + 64 + srow) * Kdim + skq;
    ushort_t* lA0 = &As[(wid * 16) * 32];
    ushort_t* lA1 = &As[(64 + wid * 16) * 32];
    ushort_t* lB0 = &Bs[(wid * 16) * 32];
    ushort_t* lB1 = &Bs[(64 + wid * 16) * 32];

    const int lr = lane & 15;
    const int kc = (lane >> 4) * 8;

    for (int k0 = 0; k0 < Kdim; k0 += 32) {
        GLL(gA0 + k0, lA0);
        GLL(gA1 + k0, lA1);
        GLL(gB0 + k0, lB0);
        GLL(gB1 + k0, lB1);
        __syncthreads();
        s8v af[4], bf[4];
        #pragma unroll
        for (int i = 0; i < 4; i++)
            af[i] = *(const s8v*)&As[(wm * 64 + i * 16 + lr) * 32 + kc];
        #pragma unroll
        for (int j = 0; j < 4; j++)
            bf[j] = *(const s8v*)&Bs[(wn * 64 + j * 16 + lr) * 32 + kc];
        #pragma unroll
        for (int i = 0; i < 4; i++)
            #pragma unroll
            for (int j = 0; j < 4; j++)
                acc[i][j] = __builtin_amdgcn_mfma_f32_16x16x32_bf16(af[i], bf[j], acc[i][j], 0, 0, 0);
        __syncthreads();
    }

    const int orow = (lane >> 4) * 4;
    #pragma unroll
    for (int j = 0; j < 4; j++) {
        int col = n0 + wn * 64 + j * 16 + lr;
        bool cok = col < Nout;
        float bb = cok ? bias[col] : 0.f;
        #pragma unroll
        for (int i = 0; i < 4; i++) {
            #pragma unroll
            for (int r = 0; r < 4; r++) {
                int row = m0 + wm * 64 + i * 16 + orow + r;
                if (cok && row < Mdim) {
                    float v = acc[i][j][r] + bb;
                    if (ACT == 1) v = 0.5f * v * (1.0f + erff(v * 0.70710678118654752f));
                    if (ACT == 2) v = 1.0f / (1.0f + expf(-v));
                    size_t idx = (size_t)row * Nout + col;
                    if (OF) Cf[idx] = v;
                    if (OB) Cb[idx] = f2b(v);
                }
            }
        }
    }
}

// ============ LayerNorm over D=512: x_f32 = LN(x + res_bf16); also write bf16 copy ============
__global__ __launch_bounds__(256) void ln_kernel(float* __restrict__ x,
                                                 const ushort_t* __restrict__ res,
                                                 const float* __restrict__ w,
                                                 const float* __restrict__ bp,
                                                 ushort_t* __restrict__ xb) {
    size_t base = (size_t)blockIdx.x * DD;
    int tid = threadIdx.x;
    float v0 = x[base + tid];
    float v1 = x[base + tid + 256];
    if (res != nullptr) { v0 += b2f(res[base + tid]); v1 += b2f(res[base + tid + 256]); }
    float s = wave_sum(v0 + v1);
    float s2 = wave_sum(v0 * v0 + v1 * v1);
    __shared__ float a1[4], a2[4];
    if ((tid & 63) == 0) { a1[tid >> 6] = s; a2[tid >> 6] = s2; }
    __syncthreads();
    s = a1[0] + a1[1] + a1[2] + a1[3];
    s2 = a2[0] + a2[1] + a2[2] + a2[3];
    float mu = s * (1.0f / DD);
    float var = s2 * (1.0f / DD) - mu * mu;
    float rs = rsqrtf(var + 1e-5f);
    float o0 = (v0 - mu) * rs * w[tid] + bp[tid];
    float o1 = (v1 - mu) * rs * w[tid + 256] + bp[tid + 256];
    x[base + tid] = o0;
    x[base + tid + 256] = o1;
    xb[base + tid] = f2b(o0);
    xb[base + tid + 256] = f2b(o1);
}

// ============ fused flow-attention normalizers: one block per (b,h) ============
// Outputs: scale_g[bh][l] = nr[l]*nrref[l];  ncref_g[bh][s] = softmax(nc_raw)*Ls
__global__ __launch_bounds__(256) void attn_stats(const ushort_t* __restrict__ Q,
                                                  const ushort_t* __restrict__ Kp,
                                                  float* __restrict__ scale_g,
                                                  float* __restrict__ ncref_g) {
    int bh = blockIdx.x;
    int b = bh >> 3, h = bh & 7;
    int tid = threadIdx.x;
    int lane = tid & 63, w = tid >> 6;
    const size_t base = ((size_t)b * LTOK) * DD + h * 64 + lane;
    __shared__ float qsum[64], ksum[64], qnsum[64], knsum[64];
    __shared__ float nrL[LTOK], ncrL[LTOK];
    __shared__ float redA[4][64], redB[4][64];

    // pass 1: column sums of q and k
    float sq = 0.f, sk = 0.f;
    for (int l = w; l < LTOK; l += 4) {
        sq += b2f(Q[base + (size_t)l * DD]);
        sk += b2f(Kp[base + (size_t)l * DD]);
    }
    redA[w][lane] = sq; redB[w][lane] = sk;
    __syncthreads();
    if (w == 0) {
        qsum[lane] = redA[0][lane] + redA[1][lane] + redA[2][lane] + redA[3][lane];
        ksum[lane] = redB[0][lane] + redB[1][lane] + redB[2][lane] + redB[3][lane];
    }
    __syncthreads();

    // pass 2: nr, nc; accumulate weighted sums
    float ks_e = ksum[lane] + 1e-6f;
    float qs_e = qsum[lane] + 1e-6f;
    float qacc = 0.f, kacc = 0.f;
    for (int l = w; l < LTOK; l += 4) {
        float qv = b2f(Q[base + (size_t)l * DD]);
        float kv = b2f(Kp[base + (size_t)l * DD]);
        float dq = wave_sum((qv + 1e-6f) * ks_e);
        float dk = wave_sum((kv + 1e-6f) * qs_e);
        float nr_l = 1.f / dq;
        float nc_l = 1.f / dk;
        if (lane == 0) nrL[l] = nr_l;
        qacc += qv * nr_l;
        kacc += kv * nc_l;
    }
    __syncthreads();
    redA[w][lane] = qacc; redB[w][lane] = kacc;
    __syncthreads();
    if (w == 0) {
        qnsum[lane] = redA[0][lane] + redA[1][lane] + redA[2][lane] + redA[3][lane];
        knsum[lane] = redB[0][lane] + redB[1][lane] + redB[2][lane] + redB[3][lane];
    }
    __syncthreads();

    // pass 3: nrref (sigmoid, Lq/Ls=1), nc_raw
    float kn_e = knsum[lane] + 1e-6f;
    float qn_e = qnsum[lane] + 1e-6f;
    for (int l = w; l < LTOK; l += 4) {
        float qv = b2f(Q[base + (size_t)l * DD]);
        float kv = b2f(Kp[base + (size_t)l * DD]);
        float dq = wave_sum((qv + 1e-6f) * kn_e);
        float dk = wave_sum((kv + 1e-6f) * qn_e);
        if (lane == 0) {
            float nrref = 1.f / (1.f + expf(-dq));
            scale_g[(size_t)bh * LTOK + l] = nrL[l] * nrref;
            ncrL[l] = dk;
        }
    }
    __syncthreads();

    // pass 4: softmax(nc_raw) * Ls
    float mx = -1e30f;
    for (int l = tid; l < LTOK; l += 256) mx = fmaxf(mx, ncrL[l]);
    #pragma unroll
    for (int off = 32; off; off >>= 1) mx = fmaxf(mx, __shfl_xor(mx, off, 64));
    if (lane == 0) redA[0][w] = mx;
    __syncthreads();
    mx = fmaxf(fmaxf(redA[0][0], redA[0][1]), fmaxf(redA[0][2], redA[0][3]));
    __syncthreads();
    float ssum = 0.f;
    for (int l = tid; l < LTOK; l += 256) ssum += expf(ncrL[l] - mx);
    ssum = wave_sum(ssum);
    if (lane == 0) redB[0][w] = ssum;
    __syncthreads();
    ssum = redB[0][0] + redB[0][1] + redB[0][2] + redB[0][3];
    float sc = (float)LTOK / ssum;
    for (int l = tid; l < LTOK; l += 256)
        ncref_g[(size_t)bh * LTOK + l] = expf(ncrL[l] - mx) * sc;
}

// ============ kv[e,d] = sum_s k[s,e]*v[s,d]*ncref[s] — barrier-free shuffle outer product ============
__global__ __launch_bounds__(256) void attn_kv(const ushort_t* __restrict__ Kp,
                                               const ushort_t* __restrict__ V,
                                               const float* __restrict__ ncref,
                                               float* __restrict__ kv) {
    int bh = blockIdx.x;
    int b = bh >> 3, h = bh & 7;
    int lane = threadIdx.x & 63, w = threadIdx.x >> 6;
    const size_t base = ((size_t)b * LTOK) * DD + h * 64 + lane;
    const float* nc = ncref + (size_t)bh * LTOK;
    float acc[16] = {};
    #pragma unroll 2
    for (int s = 0; s < LTOK; s++) {
        float kvec = b2f(Kp[base + (size_t)s * DD]);
        float vv = b2f(V[base + (size_t)s * DD]) * nc[s];
        #pragma unroll
        for (int i = 0; i < 16; i++)
            acc[i] += __shfl(kvec, w * 16 + i, 64) * vv;
    }
    #pragma unroll
    for (int i = 0; i < 16; i++)
        kv[(size_t)bh * 4096 + (size_t)(w * 16 + i) * 64 + lane] = acc[i];
}

// ============ out[l,d] = dot(q[l,:], kv[:,d]) * scale[l] — kv in registers, q via shuffle ============
__global__ __launch_bounds__(256) void attn_out(const ushort_t* __restrict__ Q,
                                                const float* __restrict__ kv,
                                                const float* __restrict__ scale_g,
                                                ushort_t* __restrict__ out) {
    int bh = blockIdx.x;
    int b = bh >> 3, h = bh & 7;
    int lane = threadIdx.x & 63, w = threadIdx.x >> 6;
    float kvreg[64];
    #pragma unroll
    for (int e = 0; e < 64; e++)
        kvreg[e] = kv[(size_t)bh * 4096 + (size_t)e * 64 + lane];
    const size_t base = ((size_t)b * LTOK) * DD + h * 64;
    int l0 = blockIdx.y * 64 + w * 16;
    for (int i = 0; i < 16; i++) {
        int l = l0 + i;
        if (l >= LTOK) break;
        float qvec = b2f(Q[base + (size_t)l * DD + lane]);
        float acc = 0.f;
        #pragma unroll
        for (int e = 0; e < 64; e++)
            acc += __shfl(qvec, e, 64) * kvreg[e];
        out[base + (size_t)l * DD + lane] = f2b(acc * scale_g[(size_t)bh * LTOK + l]);
    }
}

// ============ final: transpose from projb[NTOK,720] bf16, RevIN denorm ============
__global__ __launch_bounds__(256) void final_out(const ushort_t* __restrict__ p,
                                                 const float* __restrict__ mean,
                                                 const float* __restrict__ stdev,
                                                 const float* __restrict__ rw,
                                                 const float* __restrict__ rb,
                                                 float* __restrict__ out) {
    int b = blockIdx.z;
    int c0 = blockIdx.x * 32, t0 = blockIdx.y * 32;
    __shared__ float tile[32][33];
    int tx = threadIdx.x & 31, ty = threadIdx.x >> 5;
    #pragma unroll
    for (int kk = 0; kk < 4; kk++) {
        int c = c0 + ty + kk * 8, t = t0 + tx;
        float v = 0.f;
        if (c < CC && t < TT) v = b2f(p[((size_t)b * LTOK + c) * TT + t]);
        tile[ty + kk * 8][tx] = v;
    }
    __syncthreads();
    #pragma unroll
    for (int kk = 0; kk < 4; kk++) {
        int t = t0 + ty + kk * 8, c = c0 + tx;
        if (c < CC && t < TT) {
            float v = tile[tx][ty + kk * 8];
            v = (v - rb[c]) / (rw[c] + 1e-10f);
            v = v * stdev[b * CC + c] + mean[b * CC + c];
            out[((size_t)b * TT + t) * CC + c] = v;
        }
    }
}

extern "C" void kernel_launch(void* const* d_in, const int* in_sizes, int n_in,
                              void* d_out, int out_size, void* d_ws, size_t ws_size,
                              hipStream_t stream) {
    (void)in_sizes; (void)n_in; (void)out_size; (void)ws_size;
    const float* x_enc   = (const float*)d_in[0];
    const float* x_mark  = (const float*)d_in[1];
    const float* revin_w = (const float*)d_in[4];
    const float* revin_b = (const float*)d_in[5];
    const float* emb_W   = (const float*)d_in[6];
    const float* emb_b   = (const float*)d_in[7];
    const float* Wq = (const float*)d_in[8];
    const float* bq = (const float*)d_in[9];
    const float* Wk = (const float*)d_in[10];
    const float* bk = (const float*)d_in[11];
    const float* Wv = (const float*)d_in[12];
    const float* bv = (const float*)d_in[13];
    const float* Wo = (const float*)d_in[14];
    const float* bo = (const float*)d_in[15];
    const float* ff1_W = (const float*)d_in[16];
    const float* ff1_b = (const float*)d_in[17];
    const float* ff2_W = (const float*)d_in[18];
    const float* ff2_b = (const float*)d_in[19];
    const float* ln1_w = (const float*)d_in[20];
    const float* ln1_b = (const float*)d_in[21];
    const float* ln2_w = (const float*)d_in[22];
    const float* ln2_b = (const float*)d_in[23];
    const float* lnf_w = (const float*)d_in[24];
    const float* lnf_b = (const float*)d_in[25];
    const float* proj_W = (const float*)d_in[26];
    const float* proj_b = (const float*)d_in[27];
    float* out = (float*)d_out;

    // ---- workspace layout (~230 MB) ----
    char* wsb = (char*)d_ws;
    size_t off = 0;
    auto alloc = [&](size_t bytes) {
        off = (off + 63) & ~(size_t)63;
        void* p = wsb + off; off += bytes; return p;
    };
    float* mean  = (float*)alloc((size_t)BB * CC * 4);
    float* stdev = (float*)alloc((size_t)BB * CC * 4);
    float* scale = (float*)alloc((size_t)NBH * LTOK * 4);
    float* ncref = (float*)alloc((size_t)NBH * LTOK * 4);
    float* kvbuf = (float*)alloc((size_t)NBH * 4096 * 4);
    float* x     = (float*)alloc((size_t)NTOK * DD * 4);         // fp32 residual spine
    ushort_t* xb = (ushort_t*)alloc((size_t)NTOK * DD * 2);      // bf16 copy of x
    ushort_t* qb = (ushort_t*)alloc((size_t)NTOK * DD * 2);      // also Wo/FF2 output (tmpb)
    ushort_t* kb = (ushort_t*)alloc((size_t)NTOK * DD * 2);
    ushort_t* vb = (ushort_t*)alloc((size_t)NTOK * DD * 2);      // also attention output
    ushort_t* wbuf = (ushort_t*)alloc((size_t)10207232 * 2);     // bf16 transposed weights
    ushort_t* U  = (ushort_t*)alloc((size_t)NTOK * KPAD * 2);    // union: tokb / ff-chunk / projb

    ushort_t* embT = wbuf;                          // [512,736]
    ushort_t* qT   = embT + (size_t)512 * KPAD;     // 3 x [512,512]
    ushort_t* kT   = qT + 3 * 262144;
    ushort_t* vT   = kT + 3 * 262144;
    ushort_t* oT   = vT + 3 * 262144;
    ushort_t* f1T  = oT + 3 * 262144;               // 3 x [2048,512]
    ushort_t* f2T  = f1T + (size_t)3 * 1048576;     // 3 x [512,2048]
    ushort_t* pT   = f2T + (size_t)3 * 1048576;     // [768,512]
    ushort_t* tokb  = U;
    ushort_t* ffb   = U;
    ushort_t* projb = U;
    ushort_t* tmpb  = qb;

    dim3 blk(256);
    auto cvt = [&](const float* W, ushort_t* Wt, int K, int N, int KP, int NP) {
        convT<<<dim3((KP + 31) / 32, (NP + 31) / 32), blk, 0, stream>>>(W, Wt, K, N, KP, NP);
    };
    cvt(emb_W, embT, TT, DD, KPAD, DD);
    for (int l = 0; l < 3; l++) {
        cvt(Wq + (size_t)l * DD * DD, qT + (size_t)l * 262144, DD, DD, DD, DD);
        cvt(Wk + (size_t)l * DD * DD, kT + (size_t)l * 262144, DD, DD, DD, DD);
        cvt(Wv + (size_t)l * DD * DD, vT + (size_t)l * 262144, DD, DD, DD, DD);
        cvt(Wo + (size_t)l * DD * DD, oT + (size_t)l * 262144, DD, DD, DD, DD);
        cvt(ff1_W + (size_t)l * DD * FFD, f1T + (size_t)l * 1048576, DD, FFD, DD, FFD);
        cvt(ff2_W + (size_t)l * FFD * DD, f2T + (size_t)l * 1048576, FFD, DD, FFD, DD);
    }
    cvt(proj_W, pT, DD, TT, DD, NPADP);

    revin_stats<<<dim3((CC + 63) / 64, BB), blk, 0, stream>>>(x_enc, mean, stdev);
    build_tok<<<dim3((LTOK + 31) / 32, (KPAD + 31) / 32, BB), blk, 0, stream>>>(
        x_enc, x_mark, mean, stdev, revin_w, revin_b, tokb);
    const int MT = (NTOK + 127) / 128;   // 217
    bgemm<0, true, true><<<dim3(DD / 128, MT), blk, 0, stream>>>(
        tokb, embT, emb_b, x, xb, NTOK, KPAD, DD);

    int ltiles = (LTOK + 63) / 64;
    for (int l = 0; l < 3; l++) {
        bgemm<2, false, true><<<dim3(DD / 128, MT), blk, 0, stream>>>(
            xb, qT + (size_t)l * 262144, bq + l * DD, nullptr, qb, NTOK, DD, DD);
        bgemm<2, false, true><<<dim3(DD / 128, MT), blk, 0, stream>>>(
            xb, kT + (size_t)l * 262144, bk + l * DD, nullptr, kb, NTOK, DD, DD);
        bgemm<0, false, true><<<dim3(DD / 128, MT), blk, 0, stream>>>(
            xb, vT + (size_t)l * 262144, bv + l * DD, nullptr, vb, NTOK, DD, DD);
        attn_stats<<<NBH, blk, 0, stream>>>(qb, kb, scale, ncref);
        attn_kv<<<NBH, blk, 0, stream>>>(kb, vb, ncref, kvbuf);
        attn_out<<<dim3(NBH, ltiles), blk, 0, stream>>>(qb, kvbuf, scale, vb);
        bgemm<0, false, true><<<dim3(DD / 128, MT), blk, 0, stream>>>(
            vb, oT + (size_t)l * 262144, bo + l * DD, nullptr, tmpb, NTOK, DD, DD);
        ln_kernel<<<NTOK, blk, 0, stream>>>(x, tmpb, ln1_w + l * DD, ln1_b + l * DD, xb);
        for (int t0 = 0; t0 < NTOK / 64; t0 += 108) {
            int nt = NTOK / 64 - t0; if (nt > 108) nt = 108;
            int rs = t0 * 64, mc = nt * 64;
            bgemm<1, false, true><<<dim3(FFD / 128, (mc + 127) / 128), blk, 0, stream>>>(
                xb + (size_t)rs * DD, f1T + (size_t)l * 1048576, ff1_b + l * FFD,
                nullptr, ffb, mc, DD, FFD);
            bgemm<0, false, true><<<dim3(DD / 128, (mc + 127) / 128), blk, 0, stream>>>(
                ffb, f2T + (size_t)l * 1048576, ff2_b + l * DD,
                nullptr, tmpb + (size_t)rs * DD, mc, FFD, DD);
        }
        ln_kernel<<<NTOK, blk, 0, stream>>>(x, tmpb, ln2_w + l * DD, ln2_b + l * DD, xb);
    }
    ln_kernel<<<NTOK, blk, 0, stream>>>(x, nullptr, lnf_w, lnf_b, xb);
    bgemm<0, false, true><<<dim3(NPADP / 128, MT), blk, 0, stream>>>(
        xb, pT, proj_b, nullptr, projb, NTOK, DD, TT);
    final_out<<<dim3((CC + 31) / 32, (TT + 31) / 32, BB), blk, 0, stream>>>(
        projb, mean, stdev, revin_w, revin_b, out);
}